// Round 5
// baseline (91.236 us; speedup 1.0000x reference)
//
#include <hip/hip_runtime.h>
#include <hip/hip_bf16.h>

#define N_ROWS 32768
#define K_DIM 512
#define OUT_DIM 512
#define N_TYPES 8
#define NB 520              // max 64-row blocks after per-type padding (512 + 8)

typedef __attribute__((ext_vector_type(8))) short bf16x8;
typedef __attribute__((ext_vector_type(4))) float f32x4;

__device__ inline ushort f2bf(float f) {
    __hip_bfloat16 h = __float2bfloat16(f);
    return *reinterpret_cast<ushort*>(&h);
}

// meta layout (ints): [0..7] counts, [8..16] padded bases pbase[0..8]
//                     (pbase[8]=meta[16]=padded total), [20..27] cursors
__global__ void k_init(int* meta) {
    if (threadIdx.x < 32) meta[threadIdx.x] = 0;
}

// per-block LDS histogram -> 8 global atomics per block
__global__ void k_hist(const int* __restrict__ x_type, int* meta) {
    __shared__ int cnt[N_TYPES];
    if (threadIdx.x < N_TYPES) cnt[threadIdx.x] = 0;
    __syncthreads();
    int i = blockIdx.x * 256 + threadIdx.x;
    atomicAdd(&cnt[x_type[i]], 1);
    __syncthreads();
    if (threadIdx.x < N_TYPES && cnt[threadIdx.x] > 0)
        atomicAdd(&meta[threadIdx.x], cnt[threadIdx.x]);
}

__global__ void k_scan(int* meta) {
    if (threadIdx.x == 0) {
        int s = 0;
        for (int t = 0; t < N_TYPES; ++t) {
            meta[8 + t]  = s;      // padded base
            meta[20 + t] = s;      // cursor
            s += (meta[t] + 63) & ~63;   // pad each type segment to 64
        }
        meta[16] = s;              // padded total
    }
}

// per-block LDS hist -> reserve range with 8 global atomics -> scatter
// (row_ids pre-filled with -1; pad slots stay -1)
__global__ void k_fill(const int* __restrict__ x_type, int* meta, int* __restrict__ row_ids) {
    __shared__ int lcnt[N_TYPES];
    __shared__ int lbase[N_TYPES];
    if (threadIdx.x < N_TYPES) lcnt[threadIdx.x] = 0;
    __syncthreads();
    int i = blockIdx.x * 256 + threadIdx.x;
    int t = x_type[i];
    int lpos = atomicAdd(&lcnt[t], 1);
    __syncthreads();
    if (threadIdx.x < N_TYPES)
        lbase[threadIdx.x] = (lcnt[threadIdx.x] > 0)
            ? atomicAdd(&meta[20 + threadIdx.x], lcnt[threadIdx.x]) : 0;
    __syncthreads();
    row_ids[lbase[t] + lpos] = i;
}

// W[t][k][c] fp32 -> Wt[t][c][k] bf16   (64x64 tiles through LDS)
__global__ void k_wt(const float* __restrict__ W, ushort* __restrict__ Wt) {
    __shared__ float tile[64][65];
    int t = blockIdx.x, kb = blockIdx.y, cb = blockIdx.z;
    const float* src = W + (size_t)t * K_DIM * OUT_DIM + (size_t)kb * 64 * OUT_DIM + cb * 64;
    #pragma unroll
    for (int j = 0; j < 16; ++j) {
        int idx = threadIdx.x + j * 256;
        int r = idx >> 6, c = idx & 63;
        tile[r][c] = src[(size_t)r * OUT_DIM + c];
    }
    __syncthreads();
    ushort* dst = Wt + (size_t)t * OUT_DIM * K_DIM + (size_t)(cb * 64) * K_DIM + kb * 64;
    #pragma unroll
    for (int j = 0; j < 16; ++j) {
        int idx = threadIdx.x + j * 256;
        int cc = idx >> 6, kk = idx & 63;
        dst[(size_t)cc * K_DIM + kk] = f2bf(tile[kk][cc]);
    }
}

// 64-row x full-512-col blocks. A-panel resident in LDS (XOR-swizzled),
// B ping-pong register-prefetched from L2-resident Wt. Barrier-free K-loop.
__global__ __launch_bounds__(512, 2) void k_gemm4(
    const float* __restrict__ x, const ushort* __restrict__ Wt,
    const int* __restrict__ meta, const int* __restrict__ row_ids,
    float* __restrict__ out) {

    __shared__ ushort As[64 * K_DIM];   // 64 KB; byte addr ^= (row&7)<<4
    __shared__ int rids[64];

    int b = blockIdx.x;
    int r0 = b * 64;
    if (r0 >= meta[16]) return;         // beyond padded total
    int type = 0;
    #pragma unroll
    for (int t = 0; t < N_TYPES; ++t)
        if (r0 >= meta[8 + t]) type = t;    // last t with pbase<=r0

    int tid = threadIdx.x;
    int wave = tid >> 6, lane = tid & 63;
    int wc = wave * 64;                 // wave owns output cols [wc, wc+64)
    int lrow = lane & 15;
    int lk8 = (lane >> 4) * 8;

    if (tid < 64) rids[tid] = row_ids[r0 + tid];

    const ushort* Wtt = Wt + (size_t)type * OUT_DIM * K_DIM;
    // per-wave B base: frag (ni,s) at k-step kk lives at wb + ni*16*512 + kk + s*32
    const ushort* wb = Wtt + (size_t)(wc + lrow) * K_DIM + lk8;

    bf16x8 b0[8], b1[8];
    // B prologue for k=0 (overlaps A staging flight time)
    #pragma unroll
    for (int ni = 0; ni < 4; ++ni)
        #pragma unroll
        for (int s = 0; s < 2; ++s)
            b0[ni * 2 + s] = *reinterpret_cast<const bf16x8*>(wb + ni * 16 * K_DIM + s * 32);

    __syncthreads();    // rids visible

    // ---- stage A panel: 64 rows x 512 k, fp32 -> bf16, swizzled LDS ----
    // issue all 16 global loads first (T14), then convert + ds_write
    float4 va[8][2];
    int arow[8];
    #pragma unroll
    for (int j = 0; j < 8; ++j) {
        int f = j * 512 + tid;          // 16B-chunk index
        int row = f >> 6, c8 = f & 63;
        arow[j] = row;
        int rid = rids[row];
        if (rid >= 0) {
            const float* src = x + (size_t)rid * K_DIM + c8 * 8;
            va[j][0] = *reinterpret_cast<const float4*>(src);
            va[j][1] = *reinterpret_cast<const float4*>(src + 4);
        } else {
            va[j][0] = float4{0.f, 0.f, 0.f, 0.f};
            va[j][1] = float4{0.f, 0.f, 0.f, 0.f};
        }
    }
    #pragma unroll
    for (int j = 0; j < 8; ++j) {
        int f = j * 512 + tid;
        int row = arow[j], c8 = f & 63;
        ushort tmp[8] = { f2bf(va[j][0].x), f2bf(va[j][0].y), f2bf(va[j][0].z), f2bf(va[j][0].w),
                          f2bf(va[j][1].x), f2bf(va[j][1].y), f2bf(va[j][1].z), f2bf(va[j][1].w) };
        int byte = (row * 1024 + c8 * 16) ^ ((row & 7) << 4);
        *reinterpret_cast<uint4*>((char*)As + byte) = *reinterpret_cast<const uint4*>(tmp);
    }
    __syncthreads();
    // ---- no more barriers: A read-only, B wave-private ----

    f32x4 acc[4][4] = {};

#define LOADB(dst, kk)                                                          \
    _Pragma("unroll")                                                           \
    for (int ni = 0; ni < 4; ++ni)                                              \
        _Pragma("unroll")                                                       \
        for (int s = 0; s < 2; ++s)                                             \
            dst[ni * 2 + s] = *reinterpret_cast<const bf16x8*>(                 \
                wb + ni * 16 * K_DIM + (kk) + s * 32);

#define COMPUTE(kk, bsrc)                                                       \
    _Pragma("unroll")                                                           \
    for (int s = 0; s < 2; ++s) {                                               \
        _Pragma("unroll")                                                       \
        for (int mi = 0; mi < 4; ++mi) {                                        \
            int row = mi * 16 + lrow;                                           \
            int byte = (row * 1024 + ((kk) + s * 32 + lk8) * 2) ^ ((row & 7) << 4); \
            bf16x8 af = *reinterpret_cast<const bf16x8*>((const char*)As + byte);   \
            _Pragma("unroll")                                                   \
            for (int ni = 0; ni < 4; ++ni)                                      \
                acc[mi][ni] = __builtin_amdgcn_mfma_f32_16x16x32_bf16(          \
                    af, bsrc[ni * 2 + s], acc[mi][ni], 0, 0, 0);                \
        }                                                                       \
    }

    #pragma unroll 1
    for (int kk = 0; kk < K_DIM; kk += 128) {
        LOADB(b1, kk + 64);
        COMPUTE(kk, b0);
        if (kk + 128 < K_DIM) { LOADB(b0, kk + 128); }
        COMPUTE(kk + 64, b1);
    }

    // epilogue: D row = (lane>>4)*4 + rr, col = lane&15
    int rgrp = (lane >> 4) * 4;
    #pragma unroll
    for (int mi = 0; mi < 4; ++mi) {
        #pragma unroll
        for (int rr = 0; rr < 4; ++rr) {
            int lr = mi * 16 + rgrp + rr;
            int gr = rids[lr];
            if (gr >= 0) {
                float* dst = out + (size_t)gr * OUT_DIM + wc;
                #pragma unroll
                for (int ni = 0; ni < 4; ++ni)
                    dst[ni * 16 + lrow] = acc[mi][ni][rr];
            }
        }
    }
}

extern "C" void kernel_launch(void* const* d_in, const int* in_sizes, int n_in,
                              void* d_out, int out_size, void* d_ws, size_t ws_size,
                              hipStream_t stream) {
    const float* x      = (const float*)d_in[0];
    const int*   x_type = (const int*)d_in[1];
    const float* W      = (const float*)d_in[2];
    float* out          = (float*)d_out;

    // workspace layout
    char* ws = (char*)d_ws;
    size_t off_rids = 256;
    size_t off_wt   = off_rids + sizeof(int) * (NB * 64);   // row_ids (padded)
    int* meta    = (int*)ws;
    int* row_ids = (int*)(ws + off_rids);
    ushort* Wt   = (ushort*)(ws + off_wt);                  // 4 MB bf16

    k_init<<<1, 64, 0, stream>>>(meta);
    k_hist<<<N_ROWS / 256, 256, 0, stream>>>(x_type, meta);
    k_scan<<<1, 64, 0, stream>>>(meta);
    hipMemsetAsync(row_ids, 0xFF, sizeof(int) * (NB * 64), stream);
    k_fill<<<N_ROWS / 256, 256, 0, stream>>>(x_type, meta, row_ids);

    dim3 wgrid(N_TYPES, K_DIM / 64, OUT_DIM / 64);
    k_wt<<<wgrid, 256, 0, stream>>>(W, Wt);

    k_gemm4<<<NB, 512, 0, stream>>>(x, Wt, meta, row_ids, out);
}

// Round 6
// 64.017 us; speedup vs baseline: 1.4252x; 1.4252x over previous
//
#include <hip/hip_runtime.h>
#include <hip/hip_bf16.h>

#define N_ROWS 32768
#define K_DIM 512
#define OUT_DIM 512
#define N_TYPES 8
#define NB 520              // max 64-row blocks after per-type padding
#define BM 64
#define BN 256
#define BK 64

typedef __attribute__((ext_vector_type(8))) short bf16x8;
typedef __attribute__((ext_vector_type(4))) float f32x4;

__device__ inline ushort f2bf(float f) {
    __hip_bfloat16 h = __float2bfloat16(f);
    return *reinterpret_cast<ushort*>(&h);
}

__device__ inline void gload_lds16(const void* g, void* l) {
    __builtin_amdgcn_global_load_lds(
        (const __attribute__((address_space(1))) void*)g,
        (__attribute__((address_space(3))) void*)l, 16, 0, 0);
}

// meta layout (ints): [0..7] counts, [8..16] padded bases pbase[0..8]
//                     (pbase[8]=meta[16]=padded total), [20..27] cursors
__global__ void k_init(int* meta) {
    if (threadIdx.x < 32) meta[threadIdx.x] = 0;
}

__global__ void k_hist(const int* __restrict__ x_type, int* meta) {
    __shared__ int cnt[N_TYPES];
    if (threadIdx.x < N_TYPES) cnt[threadIdx.x] = 0;
    __syncthreads();
    int i = blockIdx.x * 256 + threadIdx.x;
    atomicAdd(&cnt[x_type[i]], 1);
    __syncthreads();
    if (threadIdx.x < N_TYPES && cnt[threadIdx.x] > 0)
        atomicAdd(&meta[threadIdx.x], cnt[threadIdx.x]);
}

__global__ void k_scan(int* meta) {
    if (threadIdx.x == 0) {
        int s = 0;
        for (int t = 0; t < N_TYPES; ++t) {
            meta[8 + t]  = s;      // padded base
            meta[20 + t] = s;      // cursor
            s += (meta[t] + 63) & ~63;   // pad each type segment to 64
        }
        meta[16] = s;              // padded total
    }
}

// per-block LDS hist -> reserve range with 8 global atomics -> scatter
// (row_ids pre-filled with -1; pad slots stay -1)
__global__ void k_fill(const int* __restrict__ x_type, int* meta, int* __restrict__ row_ids) {
    __shared__ int lcnt[N_TYPES];
    __shared__ int lbase[N_TYPES];
    if (threadIdx.x < N_TYPES) lcnt[threadIdx.x] = 0;
    __syncthreads();
    int i = blockIdx.x * 256 + threadIdx.x;
    int t = x_type[i];
    int lpos = atomicAdd(&lcnt[t], 1);
    __syncthreads();
    if (threadIdx.x < N_TYPES)
        lbase[threadIdx.x] = (lcnt[threadIdx.x] > 0)
            ? atomicAdd(&meta[20 + threadIdx.x], lcnt[threadIdx.x]) : 0;
    __syncthreads();
    row_ids[lbase[t] + lpos] = i;
}

// W[t][k][c] fp32 -> Wt[t][c][k] bf16   (64x64 tiles through LDS)
__global__ void k_wt(const float* __restrict__ W, ushort* __restrict__ Wt) {
    __shared__ float tile[64][65];
    int t = blockIdx.x, kb = blockIdx.y, cb = blockIdx.z;
    const float* src = W + (size_t)t * K_DIM * OUT_DIM + (size_t)kb * 64 * OUT_DIM + cb * 64;
    #pragma unroll
    for (int j = 0; j < 16; ++j) {
        int idx = threadIdx.x + j * 256;
        int r = idx >> 6, c = idx & 63;
        tile[r][c] = src[(size_t)r * OUT_DIM + c];
    }
    __syncthreads();
    ushort* dst = Wt + (size_t)t * OUT_DIM * K_DIM + (size_t)(cb * 64) * K_DIM + kb * 64;
    #pragma unroll
    for (int j = 0; j < 16; ++j) {
        int idx = threadIdx.x + j * 256;
        int cc = idx >> 6, kk = idx & 63;
        dst[(size_t)cc * K_DIM + kk] = f2bf(tile[kk][cc]);
    }
}

// 64x256 tiles, 8 waves, BK=64 single-buffered.  A reg-staged (fp32->bf16,
// XOR-swizzled ds_write); B via global_load_lds with pre-swizzled per-lane
// SOURCE (linear dest + swz read = rule #21).  Grid 1040 blocks -> 3 blk/CU.
__global__ __launch_bounds__(512, 6) void k_gemm5(
    const float* __restrict__ x, const ushort* __restrict__ Wt,
    const int* __restrict__ meta, const int* __restrict__ row_ids,
    float* __restrict__ out) {

    __shared__ ushort As[BM * BK];   // 8 KB   logical [row][k], byte ^= (row&7)<<4
    __shared__ ushort Bs[BN * BK];   // 32 KB  logical [col][k], byte ^= (col&7)<<4
    __shared__ int rids[BM];

    int b = blockIdx.x;
    int r0 = b * BM;
    if (r0 >= meta[16]) return;
    int type = 0;
    #pragma unroll
    for (int t = 0; t < N_TYPES; ++t)
        if (r0 >= meta[8 + t]) type = t;

    int tid = threadIdx.x;
    int wave = tid >> 6, lane = tid & 63;

    if (tid < BM) rids[tid] = row_ids[r0 + tid];
    __syncthreads();

    int c0 = blockIdx.y * BN;
    const ushort* Wtt = Wt + (size_t)type * OUT_DIM * K_DIM + (size_t)c0 * K_DIM;

    // ---- A staging role: thread -> (row, 8-elem slot) ----
    int sa_row  = tid >> 3;
    int sa_slot = tid & 7;
    int sa_rid  = rids[sa_row];
    const float* sa_src = x + (size_t)max(sa_rid, 0) * K_DIM + sa_slot * 8;
    int sa_byte = (sa_row * 128 + sa_slot * 16) ^ ((sa_row & 7) << 4);

    // ---- B staging role: per-lane source swizzle (lane-only dependent) ----
    int sb_colgrp = lane >> 3;                         // 0..7
    int sb_kbyte  = ((lane & 7) * 16) ^ (sb_colgrp << 4);

    int wrb = (wave >> 2) * 32;      // wave row base (0/32)
    int wcb = (wave & 3) * 64;       // wave col base (0..192)
    int lrow = lane & 15;
    int lkb16 = (lane >> 4) * 16;    // 16B k-fragment offset

    f32x4 acc[2][4] = {};

    #pragma unroll 1
    for (int kk = 0; kk < K_DIM; kk += BK) {
        // stage B: 4 chunks/wave, 1 KB each (8 cols x 128B)
        #pragma unroll
        for (int j = 0; j < 4; ++j) {
            int chunk = wave * 4 + j;
            int col = chunk * 8 + sb_colgrp;
            gload_lds16(Wtt + (size_t)col * K_DIM + kk + (sb_kbyte >> 1),
                        &Bs[chunk * 512]);
        }
        // stage A: load 8 fp32, convert, swizzled ds_write
        {
            ushort tmp[8] = {0, 0, 0, 0, 0, 0, 0, 0};
            if (sa_rid >= 0) {
                float4 v0 = *reinterpret_cast<const float4*>(sa_src + kk);
                float4 v1 = *reinterpret_cast<const float4*>(sa_src + kk + 4);
                tmp[0] = f2bf(v0.x); tmp[1] = f2bf(v0.y); tmp[2] = f2bf(v0.z); tmp[3] = f2bf(v0.w);
                tmp[4] = f2bf(v1.x); tmp[5] = f2bf(v1.y); tmp[6] = f2bf(v1.z); tmp[7] = f2bf(v1.w);
            }
            *reinterpret_cast<uint4*>((char*)As + sa_byte) = *reinterpret_cast<const uint4*>(tmp);
        }
        __syncthreads();

        #pragma unroll
        for (int s = 0; s < 2; ++s) {
            bf16x8 af[2], bfr[4];
            #pragma unroll
            for (int mi = 0; mi < 2; ++mi) {
                int row = wrb + mi * 16 + lrow;
                int byte = (row * 128 + s * 64 + lkb16) ^ ((row & 7) << 4);
                af[mi] = *reinterpret_cast<const bf16x8*>((const char*)As + byte);
            }
            #pragma unroll
            for (int ni = 0; ni < 4; ++ni) {
                int col = wcb + ni * 16 + lrow;
                int byte = (col * 128 + s * 64 + lkb16) ^ ((col & 7) << 4);
                bfr[ni] = *reinterpret_cast<const bf16x8*>((const char*)Bs + byte);
            }
            #pragma unroll
            for (int mi = 0; mi < 2; ++mi)
                #pragma unroll
                for (int ni = 0; ni < 4; ++ni)
                    acc[mi][ni] = __builtin_amdgcn_mfma_f32_16x16x32_bf16(
                        af[mi], bfr[ni], acc[mi][ni], 0, 0, 0);
        }
        __syncthreads();
    }

    // epilogue: D row = (lane>>4)*4 + rr, col = lane&15
    int rgrp = (lane >> 4) * 4;
    #pragma unroll
    for (int mi = 0; mi < 2; ++mi) {
        #pragma unroll
        for (int rr = 0; rr < 4; ++rr) {
            int lr = wrb + mi * 16 + rgrp + rr;
            int gr = rids[lr];
            if (gr >= 0) {
                float* dst = out + (size_t)gr * OUT_DIM + c0 + wcb;
                #pragma unroll
                for (int ni = 0; ni < 4; ++ni)
                    dst[ni * 16 + lrow] = acc[mi][ni][rr];
            }
        }
    }
}

extern "C" void kernel_launch(void* const* d_in, const int* in_sizes, int n_in,
                              void* d_out, int out_size, void* d_ws, size_t ws_size,
                              hipStream_t stream) {
    const float* x      = (const float*)d_in[0];
    const int*   x_type = (const int*)d_in[1];
    const float* W      = (const float*)d_in[2];
    float* out          = (float*)d_out;

    char* ws = (char*)d_ws;
    size_t off_rids = 256;
    size_t off_wt   = off_rids + sizeof(int) * (NB * 64);
    int* meta    = (int*)ws;
    int* row_ids = (int*)(ws + off_rids);
    ushort* Wt   = (ushort*)(ws + off_wt);                  // 4 MB bf16

    k_init<<<1, 64, 0, stream>>>(meta);
    k_hist<<<N_ROWS / 256, 256, 0, stream>>>(x_type, meta);
    k_scan<<<1, 64, 0, stream>>>(meta);
    hipMemsetAsync(row_ids, 0xFF, sizeof(int) * (NB * 64), stream);
    k_fill<<<N_ROWS / 256, 256, 0, stream>>>(x_type, meta, row_ids);

    dim3 wgrid(N_TYPES, K_DIM / 64, OUT_DIM / 64);
    k_wt<<<wgrid, 256, 0, stream>>>(W, Wt);

    dim3 ggrid(NB, OUT_DIM / BN);
    k_gemm5<<<ggrid, 512, 0, stream>>>(x, Wt, meta, row_ids, out);
}